// Round 5
// baseline (153.123 us; speedup 1.0000x reference)
//
#include <hip/hip_runtime.h>
#include <math.h>

#define NQ 12
#define DIM 4096
#define KS 6
#define BB 256
#define SEQ 128
#define DEMB 512

// Fused encoder + 6-step VQC statevector sim + head. One block per sample,
// 1024 threads, 4 complex amps per thread (16 waves/CU for latency hiding).
//
// Layout A: j = tid*4 + r  (bits 0-1 = reg -> wires 11,10; bits 2-7 = lane
//   -> wires 9..4; bits 8-11 = wave -> wires 3,2,1,0).
// Layout B (one LDS round trip, bit permutation):
//   j'_0,1 = j_8,9 (wires 3,2 -> reg)   j'_2,3 = j_10,11 (wires 1,0 -> lane)
//   j'_4..7 = j_2..5                     j'_8..11 = j_6,7,0,1 (wave)
// LDS phys addr: phys(j) = j ^ ((j>>4)&15) — conflict-free for all patterns.
// 2 __syncthreads per step. CNOT ring folded into the B->A scatter;
// Z-expvals computed pre-scatter via Walsh factorization of the ring's
// prefix-XOR sign structure.

#define REG_GATE(P, W) { \
    const float* u = &s_u[k][W][0]; \
    float u00r=u[0],u00i=u[1],u01r=u[2],u01i=u[3]; \
    float u10r=u[4],u10i=u[5],u11r=u[6],u11i=u[7]; \
    _Pragma("unroll") \
    for (int r0 = 0; r0 < 4; ++r0) if (!(r0 & (1 << (P)))) { \
        int r1 = r0 | (1 << (P)); \
        float2 A = a[r0], Bv = a[r1]; \
        a[r0].x = u00r*A.x - u00i*A.y + u01r*Bv.x - u01i*Bv.y; \
        a[r0].y = u00r*A.y + u00i*A.x + u01r*Bv.y + u01i*Bv.x; \
        a[r1].x = u10r*A.x - u10i*A.y + u11r*Bv.x - u11i*Bv.y; \
        a[r1].y = u10r*A.y + u10i*A.x + u11r*Bv.y + u11i*Bv.x; \
    } }

#define BF_PLAIN(v, m) { float p_ = __shfl_xor(v, m, 64); v = v + p_; }
#define BF_SIGN(v, m)  { float p_ = __shfl_xor(v, m, 64); float d_ = v - p_; \
                         v = (lane & m) ? -d_ : d_; }

__global__ __launch_bounds__(1024) void fused_kernel(
    const int* __restrict__ ids, const int* __restrict__ mask,
    const float* __restrict__ emb, const float* __restrict__ pw,
    const float* __restrict__ pb, const float* __restrict__ theta,
    const float* __restrict__ hw, const float* __restrict__ hb,
    float* __restrict__ readouts, float* __restrict__ logits,
    float* __restrict__ last)
{
    __shared__ float2 buf0[DIM];          // 32 KB (also enc partials 0-3)
    __shared__ float2 buf1[DIM];          // 32 KB (also enc ids/m + partials 4-7)
    __shared__ float  s_u[KS][NQ][8];
    __shared__ float  s_red[16][NQ];
    __shared__ float  s_msum[8];
    __shared__ float  s_wred[2][NQ];
    __shared__ float  s_x[NQ];
    __shared__ float  s_hw[8 * NQ];
    __shared__ float  s_hb[8];

    int b = blockIdx.x;
    int tid = threadIdx.x;
    int lane = tid & 63, wave = tid >> 6;     // wave 0..15

    // ---------------- encoder ----------------
    int*   s_ids = (int*)buf1;
    float* s_m   = (float*)buf1 + SEQ;

    if (tid < SEQ) {
        s_ids[tid] = ids[b * SEQ + tid];
        s_m[tid]   = (float)mask[b * SEQ + tid];
    }
    if (tid >= 256 && tid < 256 + 8 * NQ) s_hw[tid - 256] = hw[tid - 256];
    if (tid >= 384 && tid < 392)          s_hb[tid - 384] = hb[tid - 384];
    __syncthreads();

    {
        int g = tid >> 7, e = tid & 127;      // 8 groups of 128
        float4 acc = make_float4(0.f, 0.f, 0.f, 0.f);
        float msum = 0.f;
        #pragma unroll 4
        for (int s = g; s < SEQ; s += 8) {
            float m = s_m[s];
            float4 v = ((const float4*)emb)[(size_t)s_ids[s] * 128 + e];
            acc.x = fmaf(m, v.x, acc.x);
            acc.y = fmaf(m, v.y, acc.y);
            acc.z = fmaf(m, v.z, acc.z);
            acc.w = fmaf(m, v.w, acc.w);
            msum += m;
        }
        __syncthreads();   // ids/m reads done before overlay writes
        float4* part = (g & 4) ? (float4*)buf1 : (float4*)buf0;
        part[(g & 3) * 128 + e] = acc;
        if (e == 0) s_msum[g] = msum;
    }
    __syncthreads();

    if (tid < 128) {
        float tm = 0.f;
        #pragma unroll
        for (int i = 0; i < 8; ++i) tm += s_msum[i];
        float inv = 1.f / fmaxf(tm, 1.f);
        float4 p = make_float4(0.f, 0.f, 0.f, 0.f);
        #pragma unroll
        for (int i = 0; i < 4; ++i) {
            float4 q0 = ((float4*)buf0)[i * 128 + tid];
            float4 q1 = ((float4*)buf1)[i * 128 + tid];
            p.x += q0.x + q1.x; p.y += q0.y + q1.y;
            p.z += q0.z + q1.z; p.w += q0.w + q1.w;
        }
        p.x *= inv; p.y *= inv; p.z *= inv; p.w *= inv;
        float z[NQ];
        #pragma unroll
        for (int i = 0; i < NQ; ++i) {
            float4 w4 = ((const float4*)pw)[i * 128 + tid];
            z[i] = p.x * w4.x + p.y * w4.y + p.z * w4.z + p.w * w4.w;
        }
        #pragma unroll
        for (int i = 0; i < NQ; ++i) {
            #pragma unroll
            for (int off = 32; off > 0; off >>= 1)
                z[i] += __shfl_xor(z[i], off, 64);
        }
        if ((tid & 63) == 0) {
            int w = tid >> 6;
            #pragma unroll
            for (int i = 0; i < NQ; ++i) s_wred[w][i] = z[i];
        }
    }
    __syncthreads();
    if (tid < NQ) {
        float d = pb[tid] + s_wred[0][tid] + s_wred[1][tid];
        s_x[tid] = tanhf(d) * 3.14159274101257324f;
    }
    __syncthreads();

    // ---------------- gate matrices: U = Rot(phi,te,om) @ RY(x) ----------
    if (tid < KS * NQ) {
        int k = tid / NQ, w = tid % NQ;
        float ang = s_x[w];
        float cy = cosf(0.5f * ang), sy = sinf(0.5f * ang);
        const float* th = theta + (k * NQ + w) * 3;
        float phi = th[0], te = th[1], om = th[2];
        float ct = cosf(0.5f * te), st = sinf(0.5f * te);
        float a1 = -0.5f * (phi + om);
        float epr = cosf(a1), epi = sinf(a1);
        float a2 = 0.5f * (phi - om);
        float emr = cosf(a2), emi = sinf(a2);
        float R00r = epr * ct,  R00i = epi * ct;
        float R01r = -emr * st, R01i = -emi * st;
        float R10r = emr * st,  R10i = -emi * st;
        float R11r = epr * ct,  R11i = -epi * ct;
        s_u[k][w][0] =  R00r * cy + R01r * sy;
        s_u[k][w][1] =  R00i * cy + R01i * sy;
        s_u[k][w][2] = -R00r * sy + R01r * cy;
        s_u[k][w][3] = -R00i * sy + R01i * cy;
        s_u[k][w][4] =  R10r * cy + R11r * sy;
        s_u[k][w][5] =  R10i * cy + R11i * sy;
        s_u[k][w][6] = -R10r * sy + R11r * cy;
        s_u[k][w][7] = -R10i * sy + R11i * cy;
    }

    // ---------------- constant addresses ----------------
    int baseWA = (tid << 2) ^ ((tid >> 2) & 15);   // layout A, elem r: ^r
    int jB0 = ((lane & 3) << 10) | (((lane >> 2) & 15) << 2)
            | ((wave & 3) << 6) | ((wave >> 2) & 3);
    int baseRB = jB0 ^ (((lane >> 4) & 3) | ((wave & 3) << 2));
    int idxP[4];
    #pragma unroll
    for (int rq = 0; rq < 4; ++rq) {
        int jp = jB0 | (rq << 8);
        int b0 = (jp >> 11) & 1;
        int pref = b0, outv = 0;
        for (int w = 1; w < NQ; ++w) {
            pref ^= (jp >> (11 - w)) & 1;
            outv |= pref << (11 - w);
        }
        outv |= (b0 ^ pref) << 11;
        idxP[rq] = outv ^ ((outv >> 4) & 15);
    }
    int w0b = wave & 1, w1b = (wave >> 1) & 1;
    int w2b = (wave >> 2) & 1, w3b = (wave >> 3) & 1;
    int sW = w0b ^ w1b;

    float2 a[4];
    #pragma unroll
    for (int r = 0; r < 4; ++r) a[r] = make_float2(0.f, 0.f);
    if (tid == 0) a[0].x = 1.f;
    __syncthreads();   // s_u ready, enc buf reads done

    // ---------------- K steps ----------------
    for (int k = 0; k < KS; ++k) {
        // reg gates: wires 11 (bit0), 10 (bit1)
        REG_GATE(0, 11)
        REG_GATE(1, 10)

        // lane-shuffle gates: lane bit q = j bit q+2 = wire 9-q
        #pragma unroll
        for (int q = 0; q < 6; ++q) {
            const float* u = &s_u[k][9 - q][0];
            int mk = 1 << q;
            int bit = (lane >> q) & 1;
            float c0r = bit ? u[6] : u[0];
            float c0i = bit ? u[7] : u[1];
            float c1r = bit ? u[4] : u[2];
            float c1i = bit ? u[5] : u[3];
            #pragma unroll
            for (int r = 0; r < 4; ++r) {
                float px = __shfl_xor(a[r].x, mk, 64);
                float py = __shfl_xor(a[r].y, mk, 64);
                float nx = c0r * a[r].x - c0i * a[r].y + c1r * px - c1i * py;
                float ny = c0r * a[r].y + c0i * a[r].x + c1r * py + c1i * px;
                a[r].x = nx; a[r].y = ny;
            }
        }

        // transpose A->B
        #pragma unroll
        for (int r = 0; r < 4; ++r) buf0[baseWA ^ r] = a[r];
        __syncthreads();                                   // B1
        #pragma unroll
        for (int rq = 0; rq < 4; ++rq) a[rq] = buf0[baseRB | (rq << 8)];

        // reg gates: wires 3 (j'_0 = old bit 8), 2 (j'_1 = old bit 9)
        REG_GATE(0, 3)
        REG_GATE(1, 2)

        // lane gates: mask1 = old bit 10 = wire 1; mask2 = old bit 11 = wire 0
        #pragma unroll
        for (int q = 0; q < 2; ++q) {
            const float* u = &s_u[k][1 - q][0];
            int mk = 1 << q;
            int bit = (lane >> q) & 1;
            float c0r = bit ? u[6] : u[0];
            float c0i = bit ? u[7] : u[1];
            float c1r = bit ? u[4] : u[2];
            float c1i = bit ? u[5] : u[3];
            #pragma unroll
            for (int r = 0; r < 4; ++r) {
                float px = __shfl_xor(a[r].x, mk, 64);
                float py = __shfl_xor(a[r].y, mk, 64);
                float nx = c0r * a[r].x - c0i * a[r].y + c1r * px - c1i * py;
                float ny = c0r * a[r].y + c0i * a[r].x + c1r * py + c1i * px;
                a[r].x = nx; a[r].y = ny;
            }
        }

        // expvals PRE-scatter (Walsh factorization, new bit mapping)
        float pr0 = a[0].x*a[0].x + a[0].y*a[0].y;
        float pr1 = a[1].x*a[1].x + a[1].y*a[1].y;
        float pr2 = a[2].x*a[2].x + a[2].y*a[2].y;
        float pr3 = a[3].x*a[3].x + a[3].y*a[3].y;
        float T   = pr0 + pr1 + pr2 + pr3;              // no reg sign
        float P9  = (pr0 + pr1) - (pr2 + pr3);          // sign old bit 9
        float P98 = (pr0 + pr3) - (pr1 + pr2);          // sign old 9^8
        float v1 = T, v2 = P9, v3 = P98;
        float v6 = P98, v7 = P98, v8 = P98, v9 = P98, v0 = P98;
        // lane-sign sets: v1,v2,v3:{1,2} v6:{1,2,32} v7:{1,2,16,32}
        // v8:{1,2,8,16,32} v9:{all} v0:{1,4,8,16,32}
        BF_PLAIN(v1,32) BF_PLAIN(v2,32) BF_PLAIN(v3,32) BF_SIGN(v6,32)
        BF_SIGN(v7,32)  BF_SIGN(v8,32)  BF_SIGN(v9,32)  BF_SIGN(v0,32)
        BF_PLAIN(v1,16) BF_PLAIN(v2,16) BF_PLAIN(v3,16) BF_PLAIN(v6,16)
        BF_SIGN(v7,16)  BF_SIGN(v8,16)  BF_SIGN(v9,16)  BF_SIGN(v0,16)
        BF_PLAIN(v1,8)  BF_PLAIN(v2,8)  BF_PLAIN(v3,8)  BF_PLAIN(v6,8)
        BF_PLAIN(v7,8)  BF_SIGN(v8,8)   BF_SIGN(v9,8)   BF_SIGN(v0,8)
        BF_PLAIN(v1,4)  BF_PLAIN(v2,4)  BF_PLAIN(v3,4)  BF_PLAIN(v6,4)
        BF_PLAIN(v7,4)  BF_PLAIN(v8,4)  BF_SIGN(v9,4)   BF_SIGN(v0,4)
        BF_SIGN(v1,2)   BF_SIGN(v2,2)   BF_SIGN(v3,2)   BF_SIGN(v6,2)
        BF_SIGN(v7,2)   BF_SIGN(v8,2)   BF_SIGN(v9,2)   BF_PLAIN(v0,2)
        BF_SIGN(v1,1)   BF_SIGN(v2,1)   BF_SIGN(v3,1)   BF_SIGN(v6,1)
        BF_SIGN(v7,1)   BF_SIGN(v8,1)   BF_SIGN(v9,1)   BF_SIGN(v0,1)
        if (lane == 0) {
            float* sr = s_red[wave];
            sr[0]  = ((w0b^w1b^w2b^w3b) ? -v0 : v0);
            sr[1]  = v1;
            sr[2]  = v2;
            sr[3]  = v3;
            sr[4]  = w1b ? -v3 : v3;
            sr[5]  = sW  ? -v3 : v3;
            sr[6]  = sW  ? -v6 : v6;
            sr[7]  = sW  ? -v7 : v7;
            sr[8]  = sW  ? -v8 : v8;
            sr[9]  = sW  ? -v9 : v9;
            sr[10] = ((sW^w3b) ? -v9 : v9);
            sr[11] = ((sW^w3b^w2b) ? -v9 : v9);
        }

        // CNOT-ring permutation scatter back to layout A
        #pragma unroll
        for (int rq = 0; rq < 4; ++rq) buf1[idxP[rq]] = a[rq];
        __syncthreads();                                   // B2
        #pragma unroll
        for (int r = 0; r < 4; ++r) a[r] = buf1[baseWA ^ r];

        // finalize readouts + head
        if (tid < NQ) {
            float s = 0.f;
            #pragma unroll
            for (int w2 = 0; w2 < 16; ++w2) s += s_red[w2][tid];
            readouts[(k * BB + b) * NQ + tid] = s;
        }
        if (tid < 8) {
            float acc2 = s_hb[tid];
            #pragma unroll
            for (int i = 0; i < NQ; ++i) {
                float si = 0.f;
                #pragma unroll
                for (int w2 = 0; w2 < 16; ++w2) si += s_red[w2][i];
                acc2 = fmaf(si, s_hw[tid * NQ + i], acc2);
            }
            logits[(k * BB + b) * 8 + tid] = acc2;
            if (k == KS - 1) last[b * 8 + tid] = acc2;
        }
    }
}

extern "C" void kernel_launch(void* const* d_in, const int* in_sizes, int n_in,
                              void* d_out, int out_size, void* d_ws, size_t ws_size,
                              hipStream_t stream) {
    const int*   ids   = (const int*)d_in[0];
    const int*   mask  = (const int*)d_in[1];
    const float* emb   = (const float*)d_in[2];
    const float* pw    = (const float*)d_in[3];
    const float* pb    = (const float*)d_in[4];
    const float* theta = (const float*)d_in[5];
    const float* hw    = (const float*)d_in[6];
    const float* hb    = (const float*)d_in[7];
    float* out = (float*)d_out;

    float* readouts = out + KS * BB * 8;              // [K,B,NQ]
    float* last     = out + KS * BB * 8 + KS * BB * NQ;

    fused_kernel<<<BB, 1024, 0, stream>>>(ids, mask, emb, pw, pb, theta,
                                          hw, hb, readouts, out, last);
}

// Round 6
// 140.199 us; speedup vs baseline: 1.0922x; 1.0922x over previous
//
#include <hip/hip_runtime.h>
#include <math.h>

#define NQ 12
#define DIM 4096
#define KS 6
#define BB 256
#define SEQ 128
#define DEMB 512

// Fused encoder + 6-step VQC sim + head. 512 threads, 8 amps/thread.
// ALL 12 gates/step are register gates: four LDS "trips" rotate each
// state-bit triple into reg position. LDS image is layout-agnostic:
// amp j at phys index swz(j) = j ^ ((j>>4)&14) (conflict-free, b128-pairable).
//   L_A: reg=bits0-2 (wires 11,10,9), lane=3-8, wave=9-11
//   L_B: reg=3-5 (8,7,6), lane=(0,1,2,6,7,8), wave=9-11
//   L_C: reg=6-8 (5,4,3), lane=0-5, wave=9-11
//   L_D: reg=9-11 (2,1,0), lane=0-5, wave=6-8
// Trip4 folds the CNOT ring into its scatter; expvals computed in L_D
// pre-ring via Walsh factorization (nested suffix sign sets).

#define REG_GATE(P, W) { \
    const float* u = &s_u[k][W][0]; \
    float u00r=u[0],u00i=u[1],u01r=u[2],u01i=u[3]; \
    float u10r=u[4],u10i=u[5],u11r=u[6],u11i=u[7]; \
    _Pragma("unroll") \
    for (int r0 = 0; r0 < 8; ++r0) if (!(r0 & (1 << (P)))) { \
        int r1 = r0 | (1 << (P)); \
        float2 A = a[r0], Bv = a[r1]; \
        a[r0].x = u00r*A.x - u00i*A.y + u01r*Bv.x - u01i*Bv.y; \
        a[r0].y = u00r*A.y + u00i*A.x + u01r*Bv.y + u01i*Bv.x; \
        a[r1].x = u10r*A.x - u10i*A.y + u11r*Bv.x - u11i*Bv.y; \
        a[r1].y = u10r*A.y + u10i*A.x + u11r*Bv.y + u11i*Bv.x; \
    } }

#define BF_PLAIN(v, m) { float p_ = __shfl_xor(v, m, 64); v = v + p_; }
#define BF_SIGN(v, m)  { float p_ = __shfl_xor(v, m, 64); float d_ = v - p_; \
                         v = (lane & m) ? -d_ : d_; }

__device__ __forceinline__ int swz14(int x) { return x ^ ((x >> 4) & 14); }

__global__ __launch_bounds__(512) void fused_kernel(
    const int* __restrict__ ids, const int* __restrict__ mask,
    const float* __restrict__ emb, const float* __restrict__ pw,
    const float* __restrict__ pb, const float* __restrict__ theta,
    const float* __restrict__ hw, const float* __restrict__ hb,
    float* __restrict__ readouts, float* __restrict__ logits,
    float* __restrict__ last)
{
    __shared__ __align__(16) float2 buf0[DIM];   // 32 KB
    __shared__ __align__(16) float2 buf1[DIM];   // 32 KB
    __shared__ float  s_u[KS][NQ][8];
    __shared__ float  s_red[8][NQ];
    __shared__ float  s_msum[4];
    __shared__ float  s_wred[2][NQ];
    __shared__ float  s_x[NQ];
    __shared__ float  s_hw[8 * NQ];
    __shared__ float  s_hb[8];

    int b = blockIdx.x;
    int tid = threadIdx.x;
    int lane = tid & 63, wave = tid >> 6;     // wave 0..7

    // ---------------- encoder ----------------
    int*   s_ids = (int*)buf1;
    float* s_m   = (float*)buf1 + SEQ;
    float4* s_part = (float4*)buf0;           // [4][128]

    if (tid < SEQ) {
        s_ids[tid] = ids[b * SEQ + tid];
        s_m[tid]   = (float)mask[b * SEQ + tid];
    }
    if (tid >= 256 && tid < 256 + 8 * NQ) s_hw[tid - 256] = hw[tid - 256];
    if (tid >= 384 && tid < 392)          s_hb[tid - 384] = hb[tid - 384];
    __syncthreads();

    {
        int g = tid >> 7, e = tid & 127;
        float4 acc = make_float4(0.f, 0.f, 0.f, 0.f);
        float msum = 0.f;
        #pragma unroll 4
        for (int s = g; s < SEQ; s += 4) {
            float m = s_m[s];
            float4 v = ((const float4*)emb)[(size_t)s_ids[s] * 128 + e];
            acc.x = fmaf(m, v.x, acc.x);
            acc.y = fmaf(m, v.y, acc.y);
            acc.z = fmaf(m, v.z, acc.z);
            acc.w = fmaf(m, v.w, acc.w);
            msum += m;
        }
        __syncthreads();   // ids/m reads done before buf0 overlay write
        s_part[g * 128 + e] = acc;
        if (e == 0) s_msum[g] = msum;
    }
    __syncthreads();

    if (tid < 128) {
        float tm = fmaxf(s_msum[0] + s_msum[1] + s_msum[2] + s_msum[3], 1.f);
        float inv = 1.f / tm;
        float4 p0 = s_part[0 * 128 + tid], p1 = s_part[1 * 128 + tid];
        float4 p2 = s_part[2 * 128 + tid], p3 = s_part[3 * 128 + tid];
        float4 p;
        p.x = (p0.x + p1.x + p2.x + p3.x) * inv;
        p.y = (p0.y + p1.y + p2.y + p3.y) * inv;
        p.z = (p0.z + p1.z + p2.z + p3.z) * inv;
        p.w = (p0.w + p1.w + p2.w + p3.w) * inv;
        float z[NQ];
        #pragma unroll
        for (int i = 0; i < NQ; ++i) {
            float4 w4 = ((const float4*)pw)[i * 128 + tid];
            z[i] = p.x * w4.x + p.y * w4.y + p.z * w4.z + p.w * w4.w;
        }
        #pragma unroll
        for (int i = 0; i < NQ; ++i) {
            #pragma unroll
            for (int off = 32; off > 0; off >>= 1)
                z[i] += __shfl_xor(z[i], off, 64);
        }
        if ((tid & 63) == 0) {
            int w = tid >> 6;
            #pragma unroll
            for (int i = 0; i < NQ; ++i) s_wred[w][i] = z[i];
        }
    }
    __syncthreads();
    if (tid < NQ) {
        float d = pb[tid] + s_wred[0][tid] + s_wred[1][tid];
        s_x[tid] = tanhf(d) * 3.14159274101257324f;
    }
    __syncthreads();

    // ---------------- gate matrices: U = Rot(phi,te,om) @ RY(x) ----------
    if (tid < KS * NQ) {
        int k = tid / NQ, w = tid % NQ;
        float ang = s_x[w];
        float cy = cosf(0.5f * ang), sy = sinf(0.5f * ang);
        const float* th = theta + (k * NQ + w) * 3;
        float phi = th[0], te = th[1], om = th[2];
        float ct = cosf(0.5f * te), st = sinf(0.5f * te);
        float a1 = -0.5f * (phi + om);
        float epr = cosf(a1), epi = sinf(a1);
        float a2 = 0.5f * (phi - om);
        float emr = cosf(a2), emi = sinf(a2);
        float R00r = epr * ct,  R00i = epi * ct;
        float R01r = -emr * st, R01i = -emi * st;
        float R10r = emr * st,  R10i = -emi * st;
        float R11r = epr * ct,  R11i = -epi * ct;
        s_u[k][w][0] =  R00r * cy + R01r * sy;
        s_u[k][w][1] =  R00i * cy + R01i * sy;
        s_u[k][w][2] = -R00r * sy + R01r * cy;
        s_u[k][w][3] = -R00i * sy + R01i * cy;
        s_u[k][w][4] =  R10r * cy + R11r * sy;
        s_u[k][w][5] =  R10i * cy + R11i * sy;
        s_u[k][w][6] = -R10r * sy + R11r * cy;
        s_u[k][w][7] = -R10i * sy + R11i * cy;
    }

    // ---------------- constant addresses ----------------
    int T8 = tid << 3;
    int baseA  = swz14(T8);           // amp r at baseA^r (pairs contiguous)
    int baseA4 = baseA >> 1;          // float4 index: (baseA^2i)>>1 = baseA4^i
    int addrB[8], addrC[8], addrD[8], idxP[8];
    #pragma unroll
    for (int r = 0; r < 8; ++r) {
        addrB[r] = swz14((lane & 7) + 8 * r + 64 * (lane >> 3) + 512 * wave);
        addrC[r] = swz14(lane + 64 * r + 512 * wave);
        int jD   = lane + 64 * wave + 512 * r;
        addrD[r] = swz14(jD);
        // ring permutation of jD
        int b0 = (jD >> 11) & 1;
        int pref = b0, outv = 0;
        for (int w = 1; w < NQ; ++w) {
            pref ^= (jD >> (11 - w)) & 1;
            outv |= pref << (11 - w);
        }
        outv |= (b0 ^ pref) << 11;
        idxP[r] = swz14(outv);
    }
    int w0b = wave & 1, w1b = (wave >> 1) & 1, w2b = (wave >> 2) & 1;
    int wall = w0b ^ w1b ^ w2b;

    float2 a[8];
    #pragma unroll
    for (int r = 0; r < 8; ++r) a[r] = make_float2(0.f, 0.f);
    if (tid == 0) a[0].x = 1.f;
    __syncthreads();   // s_u ready, enc buf reads done

    // ---------------- K steps ----------------
    for (int k = 0; k < KS; ++k) {
        // phase 1 (L_A): wires 11,10,9
        REG_GATE(0, 11) REG_GATE(1, 10) REG_GATE(2, 9)

        // trip 1: A-dump (b128) -> gather L_B
        #pragma unroll
        for (int i = 0; i < 4; ++i)
            ((float4*)buf0)[baseA4 ^ i] =
                make_float4(a[2*i].x, a[2*i].y, a[2*i+1].x, a[2*i+1].y);
        __syncthreads();
        #pragma unroll
        for (int r = 0; r < 8; ++r) a[r] = buf0[addrB[r]];

        // phase 2 (L_B): wires 8,7,6
        REG_GATE(0, 8) REG_GATE(1, 7) REG_GATE(2, 6)

        // trip 2: dump L_B -> gather L_C
        #pragma unroll
        for (int r = 0; r < 8; ++r) buf1[addrB[r]] = a[r];
        __syncthreads();
        #pragma unroll
        for (int r = 0; r < 8; ++r) a[r] = buf1[addrC[r]];

        // phase 3 (L_C): wires 5,4,3
        REG_GATE(0, 5) REG_GATE(1, 4) REG_GATE(2, 3)

        // trip 3: dump L_C -> gather L_D
        #pragma unroll
        for (int r = 0; r < 8; ++r) buf0[addrC[r]] = a[r];
        __syncthreads();
        #pragma unroll
        for (int r = 0; r < 8; ++r) a[r] = buf0[addrD[r]];

        // phase 4 (L_D): wires 2,1,0
        REG_GATE(0, 2) REG_GATE(1, 1) REG_GATE(2, 0)

        // expvals PRE-ring (L_D Walsh: char of wire w = suffix-XOR of bits)
        {
            float p[8];
            #pragma unroll
            for (int r = 0; r < 8; ++r)
                p[r] = a[r].x * a[r].x + a[r].y * a[r].y;
            // reg combos (r bits = state j9,j10,j11)
            float Q1 = (p[0]+p[1]+p[6]+p[7]) - (p[2]+p[3]+p[4]+p[5]); // r1^r2
            float Q2 = (p[0]+p[3]+p[5]+p[6]) - (p[1]+p[2]+p[4]+p[7]); // parity
            float Q0 = (p[0]+p[3]+p[4]+p[7]) - (p[1]+p[2]+p[5]+p[6]); // r0^r1
            float q1 = Q1, q2p = Q2, q0 = Q0;
            BF_PLAIN(q1,32) BF_PLAIN(q1,16) BF_PLAIN(q1,8)
            BF_PLAIN(q1,4)  BF_PLAIN(q1,2)  BF_PLAIN(q1,1)
            BF_PLAIN(q2p,32) BF_PLAIN(q2p,16) BF_PLAIN(q2p,8)
            BF_PLAIN(q2p,4)  BF_PLAIN(q2p,2)  BF_PLAIN(q2p,1)
            BF_SIGN(q0,32) BF_SIGN(q0,16) BF_SIGN(q0,8)
            BF_SIGN(q0,4)  BF_SIGN(q0,2)  BF_SIGN(q0,1)
            // nested-suffix chain on Q2 (signs from mask 32 down)
            float c = Q2;
            BF_SIGN(c,32);
            float w6v = c; BF_PLAIN(w6v,16) BF_PLAIN(w6v,8) BF_PLAIN(w6v,4)
                           BF_PLAIN(w6v,2)  BF_PLAIN(w6v,1)
            BF_SIGN(c,16);
            float w7v = c; BF_PLAIN(w7v,8) BF_PLAIN(w7v,4)
                           BF_PLAIN(w7v,2) BF_PLAIN(w7v,1)
            BF_SIGN(c,8);
            float w8v = c; BF_PLAIN(w8v,4) BF_PLAIN(w8v,2) BF_PLAIN(w8v,1)
            BF_SIGN(c,4);
            float w9v = c; BF_PLAIN(w9v,2) BF_PLAIN(w9v,1)
            BF_SIGN(c,2);
            float w10v = c; BF_PLAIN(w10v,1)
            BF_SIGN(c,1);                       // c = wire-11 value
            if (lane == 0) {
                float* sr = s_red[wave];
                sr[0]  = wall ? -q0  : q0;
                sr[1]  = q1;
                sr[2]  = q2p;
                sr[3]  = w2b ? -q2p : q2p;
                sr[4]  = (w1b ^ w2b) ? -q2p : q2p;
                sr[5]  = wall ? -q2p : q2p;
                sr[6]  = wall ? -w6v : w6v;
                sr[7]  = wall ? -w7v : w7v;
                sr[8]  = wall ? -w8v : w8v;
                sr[9]  = wall ? -w9v : w9v;
                sr[10] = wall ? -w10v : w10v;
                sr[11] = wall ? -c   : c;
            }
        }

        // trip 4: ring scatter -> gather L_A (b128)
        #pragma unroll
        for (int r = 0; r < 8; ++r) buf1[idxP[r]] = a[r];
        __syncthreads();
        #pragma unroll
        for (int i = 0; i < 4; ++i) {
            float4 v = ((float4*)buf1)[baseA4 ^ i];
            a[2*i]   = make_float2(v.x, v.y);
            a[2*i+1] = make_float2(v.z, v.w);
        }

        // finalize readouts + head (overlaps next step's phase-1 gates)
        if (tid < NQ) {
            float s = 0.f;
            #pragma unroll
            for (int w2 = 0; w2 < 8; ++w2) s += s_red[w2][tid];
            readouts[(k * BB + b) * NQ + tid] = s;
        }
        if (tid < 8) {
            float acc2 = s_hb[tid];
            #pragma unroll
            for (int i = 0; i < NQ; ++i) {
                float si = 0.f;
                #pragma unroll
                for (int w2 = 0; w2 < 8; ++w2) si += s_red[w2][i];
                acc2 = fmaf(si, s_hw[tid * NQ + i], acc2);
            }
            logits[(k * BB + b) * 8 + tid] = acc2;
            if (k == KS - 1) last[b * 8 + tid] = acc2;
        }
    }
}

extern "C" void kernel_launch(void* const* d_in, const int* in_sizes, int n_in,
                              void* d_out, int out_size, void* d_ws, size_t ws_size,
                              hipStream_t stream) {
    const int*   ids   = (const int*)d_in[0];
    const int*   mask  = (const int*)d_in[1];
    const float* emb   = (const float*)d_in[2];
    const float* pw    = (const float*)d_in[3];
    const float* pb    = (const float*)d_in[4];
    const float* theta = (const float*)d_in[5];
    const float* hw    = (const float*)d_in[6];
    const float* hb    = (const float*)d_in[7];
    float* out = (float*)d_out;

    float* readouts = out + KS * BB * 8;              // [K,B,NQ]
    float* last     = out + KS * BB * 8 + KS * BB * NQ;

    fused_kernel<<<BB, 512, 0, stream>>>(ids, mask, emb, pw, pb, theta,
                                         hw, hb, readouts, out, last);
}

// Round 7
// 139.872 us; speedup vs baseline: 1.0947x; 1.0023x over previous
//
#include <hip/hip_runtime.h>
#include <math.h>

#define NQ 12
#define DIM 4096
#define KS 6
#define BB 256
#define SEQ 128
#define DEMB 512

// Fused encoder + 6-step VQC sim + head. 512 threads, 8 amps/thread.
// All 12 gates/step are register gates via four layout trips; trips 1-2 are
// INTRA-WAVE (wave = state bits 9-11 in layouts A,B,C) -> no __syncthreads,
// just s_waitcnt lgkmcnt(0). Only trip 3 (bits 9-11 -> regs) and trip 4
// (CNOT-ring scatter) cross waves: 2 barriers/step.
// LDS image layout-agnostic: amp j at phys swz(j) = j ^ ((j>>4)&14).
//   L_A: reg=bits0-2 (wires 11,10,9), lane=3-8, wave=9-11
//   L_B: reg=3-5 (8,7,6), lane=(0,1,2,6,7,8), wave=9-11
//   L_C: reg=6-8 (5,4,3), lane=0-5, wave=9-11
//   L_D: reg=9-11 (2,1,0), lane=0-5, wave=6-8
// Ring folded into trip-4 scatter; expvals pre-ring via Walsh factorization.

#define REG_GATE(P, W) { \
    float4 c0 = *(const float4*)&s_u[k][W][0]; \
    float4 c1 = *(const float4*)&s_u[k][W][4]; \
    float u00r=c0.x,u00i=c0.y,u01r=c0.z,u01i=c0.w; \
    float u10r=c1.x,u10i=c1.y,u11r=c1.z,u11i=c1.w; \
    _Pragma("unroll") \
    for (int r0 = 0; r0 < 8; ++r0) if (!(r0 & (1 << (P)))) { \
        int r1 = r0 | (1 << (P)); \
        float2 A = a[r0], Bv = a[r1]; \
        a[r0].x = u00r*A.x - u00i*A.y + u01r*Bv.x - u01i*Bv.y; \
        a[r0].y = u00r*A.y + u00i*A.x + u01r*Bv.y + u01i*Bv.x; \
        a[r1].x = u10r*A.x - u10i*A.y + u11r*Bv.x - u11i*Bv.y; \
        a[r1].y = u10r*A.y + u10i*A.x + u11r*Bv.y + u11i*Bv.x; \
    } }

#define BF_PLAIN(v, m) { float p_ = __shfl_xor(v, m, 64); v = v + p_; }
#define BF_SIGN(v, m)  { float p_ = __shfl_xor(v, m, 64); float d_ = v - p_; \
                         v = (lane & m) ? -d_ : d_; }

// wave-local LDS write->read ordering (no block barrier)
#define WAVE_FENCE() asm volatile("s_waitcnt lgkmcnt(0)" ::: "memory")

__device__ __forceinline__ int swz14(int x) { return x ^ ((x >> 4) & 14); }

__global__ __launch_bounds__(512) void fused_kernel(
    const int* __restrict__ ids, const int* __restrict__ mask,
    const float* __restrict__ emb, const float* __restrict__ pw,
    const float* __restrict__ pb, const float* __restrict__ theta,
    const float* __restrict__ hw, const float* __restrict__ hb,
    float* __restrict__ readouts, float* __restrict__ logits,
    float* __restrict__ last)
{
    __shared__ __align__(16) float2 buf0[DIM];   // 32 KB (trips 1-3)
    __shared__ __align__(16) float2 buf1[DIM];   // 32 KB (trip 4 / enc)
    __shared__ __align__(16) float  s_u[KS][NQ][8];
    __shared__ float  s_red[8][NQ];
    __shared__ float  s_msum[4];
    __shared__ float  s_wred[2][NQ];
    __shared__ float  s_x[NQ];
    __shared__ float  s_hw[8 * NQ];
    __shared__ float  s_hb[8];

    int b = blockIdx.x;
    int tid = threadIdx.x;
    int lane = tid & 63, wave = tid >> 6;     // wave 0..7

    // ---------------- encoder ----------------
    int*   s_ids = (int*)buf1;
    float* s_m   = (float*)buf1 + SEQ;
    float4* s_part = (float4*)buf0;           // [4][128]

    if (tid < SEQ) {
        s_ids[tid] = ids[b * SEQ + tid];
        s_m[tid]   = (float)mask[b * SEQ + tid];
    }
    if (tid >= 256 && tid < 256 + 8 * NQ) s_hw[tid - 256] = hw[tid - 256];
    if (tid >= 384 && tid < 392)          s_hb[tid - 384] = hb[tid - 384];
    __syncthreads();

    {
        int g = tid >> 7, e = tid & 127;
        float4 acc = make_float4(0.f, 0.f, 0.f, 0.f);
        float msum = 0.f;
        #pragma unroll 4
        for (int s = g; s < SEQ; s += 4) {
            float m = s_m[s];
            float4 v = ((const float4*)emb)[(size_t)s_ids[s] * 128 + e];
            acc.x = fmaf(m, v.x, acc.x);
            acc.y = fmaf(m, v.y, acc.y);
            acc.z = fmaf(m, v.z, acc.z);
            acc.w = fmaf(m, v.w, acc.w);
            msum += m;
        }
        __syncthreads();   // ids/m reads done before buf0 overlay write
        s_part[g * 128 + e] = acc;
        if (e == 0) s_msum[g] = msum;
    }
    __syncthreads();

    if (tid < 128) {
        float tm = fmaxf(s_msum[0] + s_msum[1] + s_msum[2] + s_msum[3], 1.f);
        float inv = 1.f / tm;
        float4 p0 = s_part[0 * 128 + tid], p1 = s_part[1 * 128 + tid];
        float4 p2 = s_part[2 * 128 + tid], p3 = s_part[3 * 128 + tid];
        float4 p;
        p.x = (p0.x + p1.x + p2.x + p3.x) * inv;
        p.y = (p0.y + p1.y + p2.y + p3.y) * inv;
        p.z = (p0.z + p1.z + p2.z + p3.z) * inv;
        p.w = (p0.w + p1.w + p2.w + p3.w) * inv;
        float z[NQ];
        #pragma unroll
        for (int i = 0; i < NQ; ++i) {
            float4 w4 = ((const float4*)pw)[i * 128 + tid];
            z[i] = p.x * w4.x + p.y * w4.y + p.z * w4.z + p.w * w4.w;
        }
        #pragma unroll
        for (int i = 0; i < NQ; ++i) {
            #pragma unroll
            for (int off = 32; off > 0; off >>= 1)
                z[i] += __shfl_xor(z[i], off, 64);
        }
        if ((tid & 63) == 0) {
            int w = tid >> 6;
            #pragma unroll
            for (int i = 0; i < NQ; ++i) s_wred[w][i] = z[i];
        }
    }
    __syncthreads();
    if (tid < NQ) {
        float d = pb[tid] + s_wred[0][tid] + s_wred[1][tid];
        s_x[tid] = tanhf(d) * 3.14159274101257324f;
    }
    __syncthreads();

    // ---------------- gate matrices: U = Rot(phi,te,om) @ RY(x) ----------
    if (tid < KS * NQ) {
        int k = tid / NQ, w = tid % NQ;
        float ang = s_x[w];
        float cy = cosf(0.5f * ang), sy = sinf(0.5f * ang);
        const float* th = theta + (k * NQ + w) * 3;
        float phi = th[0], te = th[1], om = th[2];
        float ct = cosf(0.5f * te), st = sinf(0.5f * te);
        float a1 = -0.5f * (phi + om);
        float epr = cosf(a1), epi = sinf(a1);
        float a2 = 0.5f * (phi - om);
        float emr = cosf(a2), emi = sinf(a2);
        float R00r = epr * ct,  R00i = epi * ct;
        float R01r = -emr * st, R01i = -emi * st;
        float R10r = emr * st,  R10i = -emi * st;
        float R11r = epr * ct,  R11i = -epi * ct;
        s_u[k][w][0] =  R00r * cy + R01r * sy;
        s_u[k][w][1] =  R00i * cy + R01i * sy;
        s_u[k][w][2] = -R00r * sy + R01r * cy;
        s_u[k][w][3] = -R00i * sy + R01i * cy;
        s_u[k][w][4] =  R10r * cy + R11r * sy;
        s_u[k][w][5] =  R10i * cy + R11i * sy;
        s_u[k][w][6] = -R10r * sy + R11r * cy;
        s_u[k][w][7] = -R10i * sy + R11i * cy;
    }

    // ---------------- constant addresses ----------------
    int T8 = tid << 3;
    int baseA  = swz14(T8);
    int baseA4 = baseA >> 1;          // float4 index; elem i at baseA4^i
    int addrB[8], addrC[8], addrD[8], idxP[8];
    #pragma unroll
    for (int r = 0; r < 8; ++r) {
        addrB[r] = swz14((lane & 7) + 8 * r + 64 * (lane >> 3) + 512 * wave);
        addrC[r] = swz14(lane + 64 * r + 512 * wave);
        int jD   = lane + 64 * wave + 512 * r;
        addrD[r] = swz14(jD);
        int b0 = (jD >> 11) & 1;
        int pref = b0, outv = 0;
        for (int w = 1; w < NQ; ++w) {
            pref ^= (jD >> (11 - w)) & 1;
            outv |= pref << (11 - w);
        }
        outv |= (b0 ^ pref) << 11;
        idxP[r] = swz14(outv);
    }
    int w0b = wave & 1, w1b = (wave >> 1) & 1, w2b = (wave >> 2) & 1;
    int wall = w0b ^ w1b ^ w2b;

    float2 a[8];
    #pragma unroll
    for (int r = 0; r < 8; ++r) a[r] = make_float2(0.f, 0.f);
    if (tid == 0) a[0].x = 1.f;
    __syncthreads();   // s_u ready, enc buf reads done

    // ---------------- K steps ----------------
    for (int k = 0; k < KS; ++k) {
        // phase 1 (L_A): wires 11,10,9
        REG_GATE(0, 11) REG_GATE(1, 10) REG_GATE(2, 9)

        // trip 1 (intra-wave): b128 dump -> gather L_B
        #pragma unroll
        for (int i = 0; i < 4; ++i)
            ((float4*)buf0)[baseA4 ^ i] =
                make_float4(a[2*i].x, a[2*i].y, a[2*i+1].x, a[2*i+1].y);
        WAVE_FENCE();
        #pragma unroll
        for (int r = 0; r < 8; ++r) a[r] = buf0[addrB[r]];

        // phase 2 (L_B): wires 8,7,6
        REG_GATE(0, 8) REG_GATE(1, 7) REG_GATE(2, 6)

        // trip 2 (intra-wave): dump L_B -> gather L_C
        #pragma unroll
        for (int r = 0; r < 8; ++r) buf0[addrB[r]] = a[r];
        WAVE_FENCE();
        #pragma unroll
        for (int r = 0; r < 8; ++r) a[r] = buf0[addrC[r]];

        // phase 3 (L_C): wires 5,4,3
        REG_GATE(0, 5) REG_GATE(1, 4) REG_GATE(2, 3)

        // trip 3 (cross-wave): dump L_C -> barrier -> gather L_D
        #pragma unroll
        for (int r = 0; r < 8; ++r) buf0[addrC[r]] = a[r];
        __syncthreads();                                   // B1
        #pragma unroll
        for (int r = 0; r < 8; ++r) a[r] = buf0[addrD[r]];

        // phase 4 (L_D): wires 2,1,0
        REG_GATE(0, 2) REG_GATE(1, 1) REG_GATE(2, 0)

        // trip 4: issue ring scatter FIRST (drains while expvals shuffle)
        #pragma unroll
        for (int r = 0; r < 8; ++r) buf1[idxP[r]] = a[r];

        // expvals PRE-ring (L_D Walsh; signs verified in R6)
        {
            float p[8];
            #pragma unroll
            for (int r = 0; r < 8; ++r)
                p[r] = a[r].x * a[r].x + a[r].y * a[r].y;
            float Q1 = (p[0]+p[1]+p[6]+p[7]) - (p[2]+p[3]+p[4]+p[5]);
            float Q2 = (p[0]+p[3]+p[5]+p[6]) - (p[1]+p[2]+p[4]+p[7]);
            float Q0 = (p[0]+p[3]+p[4]+p[7]) - (p[1]+p[2]+p[5]+p[6]);
            float q1 = Q1, q2p = Q2, q0 = Q0;
            BF_PLAIN(q1,32) BF_PLAIN(q1,16) BF_PLAIN(q1,8)
            BF_PLAIN(q1,4)  BF_PLAIN(q1,2)  BF_PLAIN(q1,1)
            BF_PLAIN(q2p,32) BF_PLAIN(q2p,16) BF_PLAIN(q2p,8)
            BF_PLAIN(q2p,4)  BF_PLAIN(q2p,2)  BF_PLAIN(q2p,1)
            BF_SIGN(q0,32) BF_SIGN(q0,16) BF_SIGN(q0,8)
            BF_SIGN(q0,4)  BF_SIGN(q0,2)  BF_SIGN(q0,1)
            float c = Q2;
            BF_SIGN(c,32);
            float w6v = c; BF_PLAIN(w6v,16) BF_PLAIN(w6v,8) BF_PLAIN(w6v,4)
                           BF_PLAIN(w6v,2)  BF_PLAIN(w6v,1)
            BF_SIGN(c,16);
            float w7v = c; BF_PLAIN(w7v,8) BF_PLAIN(w7v,4)
                           BF_PLAIN(w7v,2) BF_PLAIN(w7v,1)
            BF_SIGN(c,8);
            float w8v = c; BF_PLAIN(w8v,4) BF_PLAIN(w8v,2) BF_PLAIN(w8v,1)
            BF_SIGN(c,4);
            float w9v = c; BF_PLAIN(w9v,2) BF_PLAIN(w9v,1)
            BF_SIGN(c,2);
            float w10v = c; BF_PLAIN(w10v,1)
            BF_SIGN(c,1);
            if (lane == 0) {
                float* sr = s_red[wave];
                sr[0]  = wall ? -q0  : q0;
                sr[1]  = q1;
                sr[2]  = q2p;
                sr[3]  = w2b ? -q2p : q2p;
                sr[4]  = (w1b ^ w2b) ? -q2p : q2p;
                sr[5]  = wall ? -q2p : q2p;
                sr[6]  = wall ? -w6v : w6v;
                sr[7]  = wall ? -w7v : w7v;
                sr[8]  = wall ? -w8v : w8v;
                sr[9]  = wall ? -w9v : w9v;
                sr[10] = wall ? -w10v : w10v;
                sr[11] = wall ? -c   : c;
            }
        }

        __syncthreads();                                   // B2
        #pragma unroll
        for (int i = 0; i < 4; ++i) {
            float4 v = ((float4*)buf1)[baseA4 ^ i];
            a[2*i]   = make_float2(v.x, v.y);
            a[2*i+1] = make_float2(v.z, v.w);
        }

        // finalize readouts + head (overlaps next step's phase-1 gates)
        if (tid < NQ) {
            float s = 0.f;
            #pragma unroll
            for (int w2 = 0; w2 < 8; ++w2) s += s_red[w2][tid];
            readouts[(k * BB + b) * NQ + tid] = s;
        }
        if (tid < 8) {
            float acc2 = s_hb[tid];
            #pragma unroll
            for (int i = 0; i < NQ; ++i) {
                float si = 0.f;
                #pragma unroll
                for (int w2 = 0; w2 < 8; ++w2) si += s_red[w2][i];
                acc2 = fmaf(si, s_hw[tid * NQ + i], acc2);
            }
            logits[(k * BB + b) * 8 + tid] = acc2;
            if (k == KS - 1) last[b * 8 + tid] = acc2;
        }
    }
}

extern "C" void kernel_launch(void* const* d_in, const int* in_sizes, int n_in,
                              void* d_out, int out_size, void* d_ws, size_t ws_size,
                              hipStream_t stream) {
    const int*   ids   = (const int*)d_in[0];
    const int*   mask  = (const int*)d_in[1];
    const float* emb   = (const float*)d_in[2];
    const float* pw    = (const float*)d_in[3];
    const float* pb    = (const float*)d_in[4];
    const float* theta = (const float*)d_in[5];
    const float* hw    = (const float*)d_in[6];
    const float* hb    = (const float*)d_in[7];
    float* out = (float*)d_out;

    float* readouts = out + KS * BB * 8;              // [K,B,NQ]
    float* last     = out + KS * BB * 8 + KS * BB * NQ;

    fused_kernel<<<BB, 512, 0, stream>>>(ids, mask, emb, pw, pb, theta,
                                         hw, hb, readouts, out, last);
}